// Round 13
// baseline (264.655 us; speedup 1.0000x reference)
//
#include <hip/hip_runtime.h>

#define D_MODEL 1024
#define SEQ 2048
#define BATCH 2
#define NH 16
#define DH 64
#define WIN 128
#define DFF 3072

typedef __bf16 bf16x8 __attribute__((ext_vector_type(8)));
typedef float f32x4 __attribute__((ext_vector_type(4)));
typedef unsigned short u16;
typedef unsigned int u32;

__device__ __forceinline__ float b2f(u16 u) {
    unsigned int x = ((unsigned int)u) << 16;
    return __uint_as_float(x);
}
__device__ __forceinline__ u16 f2b(float f) {
    unsigned int x = __float_as_uint(f);
    x += 0x7fffu + ((x >> 16) & 1u);
    return (u16)(x >> 16);
}
__device__ __forceinline__ u32 pk2(float a, float b) {
    return (u32)f2b(a) | ((u32)f2b(b) << 16);
}

// s_waitcnt imm: vmcnt[3:0]|[15:14], exp[6:4], lgkm[11:8]. vmcnt(0), no
// exp/lgkm wait: 0x0F70.
#define WAIT_VMCNT0() __builtin_amdgcn_s_waitcnt(0x0F70)

// ---------------------------------------------------------------- prep
// Fused: 4 weight transposes (f32 -> bf16, [R][C] -> [C][R], 64x64 tiles,
// float4 reads, ushort4 stores) + LN1 (float4 loads).
// Ranges: [0,768) wqkv, [768,1024) wout, [1024,1792) wff1,
//         [1792,2560) wff2, [2560,6656) LN1 rows.
__global__ __launch_bounds__(256) void prep_k(
        const float* __restrict__ x, const float* __restrict__ g1,
        const float* __restrict__ bt1, u16* __restrict__ hbf,
        const float* __restrict__ wqkv, u16* __restrict__ wqkvT,
        const float* __restrict__ wout, u16* __restrict__ woutT,
        const float* __restrict__ wff1, u16* __restrict__ wff1T,
        const float* __restrict__ wff2, u16* __restrict__ wff2T) {
    __shared__ u16 tile[64][65];
    __shared__ float s1[4], s2[4];
    int bid = blockIdx.x;
    int tid = threadIdx.x;
    if (bid < 2560) {
        const float* in; u16* out; int R, C, loc, gx;
        if (bid < 768)       { in = wqkv; out = wqkvT; R = 1024; C = 3072; loc = bid;        gx = 48; }
        else if (bid < 1024) { in = wout; out = woutT; R = 1024; C = 1024; loc = bid - 768;  gx = 16; }
        else if (bid < 1792) { in = wff1; out = wff1T; R = 1024; C = 3072; loc = bid - 1024; gx = 48; }
        else                 { in = wff2; out = wff2T; R = 3072; C = 1024; loc = bid - 1792; gx = 16; }
        int bx = loc % gx, by = loc / gx;
        int r0 = by * 64, c0 = bx * 64;
        int fl = tid & 15, rw = tid >> 4;      // 16 float4-cols x 16 rows
#pragma unroll
        for (int j = 0; j < 4; ++j) {
            int r = j * 16 + rw;
            float4 v4 = *(const float4*)&in[(size_t)(r0 + r) * C + c0 + fl * 4];
            tile[r][fl * 4 + 0] = f2b(v4.x);
            tile[r][fl * 4 + 1] = f2b(v4.y);
            tile[r][fl * 4 + 2] = f2b(v4.z);
            tile[r][fl * 4 + 3] = f2b(v4.w);
        }
        __syncthreads();
        int rr = (tid & 15) * 4;
        int cb = tid >> 4;                     // 0..15
#pragma unroll
        for (int j = 0; j < 4; ++j) {
            int c = cb + j * 16;
            ushort4 p = {tile[rr][c], tile[rr + 1][c],
                         tile[rr + 2][c], tile[rr + 3][c]};
            *(ushort4*)&out[(size_t)(c0 + c) * R + r0 + rr] = p;
        }
    } else {
        int row = bid - 2560;
        float4 v = ((const float4*)(x + (size_t)row * D_MODEL))[tid];
        float sum = v.x + v.y + v.z + v.w;
        float sq  = v.x * v.x + v.y * v.y + v.z * v.z + v.w * v.w;
#pragma unroll
        for (int off = 32; off > 0; off >>= 1) {
            sum += __shfl_xor(sum, off, 64);
            sq  += __shfl_xor(sq, off, 64);
        }
        int w = tid >> 6;
        if ((tid & 63) == 0) { s1[w] = sum; s2[w] = sq; }
        __syncthreads();
        sum = s1[0] + s1[1] + s1[2] + s1[3];
        sq  = s2[0] + s2[1] + s2[2] + s2[3];
        float mu = sum * (1.f / D_MODEL);
        float var = sq * (1.f / D_MODEL) - mu * mu;
        float rstd = rsqrtf(var + 1e-5f);
        float4 gg = ((const float4*)g1)[tid];
        float4 bb = ((const float4*)bt1)[tid];
        ushort4 o = {f2b((v.x - mu) * rstd * gg.x + bb.x),
                     f2b((v.y - mu) * rstd * gg.y + bb.y),
                     f2b((v.z - mu) * rstd * gg.z + bb.z),
                     f2b((v.w - mu) * rstd * gg.w + bb.w)};
        *(ushort4*)&hbf[(size_t)row * D_MODEL + tid * 4] = o;
    }
}

// ---------------------------------------------------------------- layernorm
// float4 loads: 256 threads x 1 float4 = one 1024-wide row.
__global__ __launch_bounds__(256) void ln_k(
        const float* __restrict__ x, const float* __restrict__ g,
        const float* __restrict__ bta, u16* __restrict__ out) {
    int row = blockIdx.x;
    int tid = threadIdx.x;
    float4 v = ((const float4*)(x + (size_t)row * D_MODEL))[tid];
    float sum = v.x + v.y + v.z + v.w;
    float sq  = v.x * v.x + v.y * v.y + v.z * v.z + v.w * v.w;
#pragma unroll
    for (int off = 32; off > 0; off >>= 1) {
        sum += __shfl_xor(sum, off, 64);
        sq  += __shfl_xor(sq, off, 64);
    }
    __shared__ float s1[4], s2[4];
    int w = tid >> 6;
    if ((tid & 63) == 0) { s1[w] = sum; s2[w] = sq; }
    __syncthreads();
    sum = s1[0] + s1[1] + s1[2] + s1[3];
    sq  = s2[0] + s2[1] + s2[2] + s2[3];
    float mu = sum * (1.f / D_MODEL);
    float var = sq * (1.f / D_MODEL) - mu * mu;
    float rstd = rsqrtf(var + 1e-5f);
    float4 gg = ((const float4*)g)[tid];
    float4 bb = ((const float4*)bta)[tid];
    ushort4 o = {f2b((v.x - mu) * rstd * gg.x + bb.x),
                 f2b((v.y - mu) * rstd * gg.y + bb.y),
                 f2b((v.z - mu) * rstd * gg.z + bb.z),
                 f2b((v.w - mu) * rstd * gg.w + bb.w)};
    *(ushort4*)&out[(size_t)row * D_MODEL + tid * 4] = o;
}

// ---------------------------------------------------------------- GEMM 128^2
// For QKV/FF1 (N=3072). R12-proven: 128x128 tile, single-buffer skeleton
// {stage -> vmcnt(0) -> barrier -> ds_read+MFMA -> barrier}. 32 KiB LDS;
// grid = 32x24 = 768 = exactly 3 blocks/CU. 0.5 ds_read/MFMA. XOR bank
// swizzle (conflicts=0). NO setprio (R10: 10x L2-thrash in lockstep).
template <int GELU, int VSPLIT>
__global__ __launch_bounds__(256, 3) void gemm3_k(
        const u16* __restrict__ A, const u16* __restrict__ Bt,
        const float* __restrict__ bias, u16* __restrict__ Cb,
        u16* __restrict__ vt, int M, int N, int K, int ldc) {
    __shared__ u16 As[128 * 64];               // 16 KiB
    __shared__ u16 Bs[128 * 64];               // 16 KiB
    int tid = threadIdx.x;
    int w = tid >> 6, lane = tid & 63;
    int qd = lane >> 4, l15 = lane & 15;

    // grid = (M/128)*(N/128) = 32*24 = 768. XCD-stripe: 4 m-tiles per XCD
    // (512-row, 1 MiB A stripe stays L2-local per XCD).
    int lin = blockIdx.x;
    int xcd = lin & 7, idx = lin >> 3;         // idx 0..95
    int m0 = (xcd * 4 + (idx & 3)) * 128;
    int n0 = (idx >> 2) * 128;

    // Staging: 32 chunks of 1 KiB (8 rows x 64 cols); wave owns 8.
    // chunks 0-15 = A (128 rows), 16-31 = B (128 rows).
    const u16* gsrc[8];
    u16* ldst[8];
#pragma unroll
    for (int i = 0; i < 8; ++i) {
        int c = w * 8 + i;                     // 0..31
        int cb = c & 15;
        int row = cb * 8 + (lane >> 3);
        int cg = (lane & 7) ^ (row & 7);       // XOR swizzle, global side
        gsrc[i] = (c < 16 ? A + (size_t)(m0 + row) * K
                          : Bt + (size_t)(n0 + row) * K) + cg * 8;
        ldst[i] = (c < 16 ? As : Bs) + cb * 512;
    }

    int wm = w & 1, wn = w >> 1;               // 2x2 waves, 64x64 each
    f32x4 acc[4][4];
#pragma unroll
    for (int mt = 0; mt < 4; ++mt)
#pragma unroll
        for (int nt = 0; nt < 4; ++nt)
            acc[mt][nt] = (f32x4){0.f, 0.f, 0.f, 0.f};

    int aoff[4][2], boff[4][2];
#pragma unroll
    for (int t = 0; t < 4; ++t) {
        int ar = wm * 64 + t * 16 + l15;
        int br = wn * 64 + t * 16 + l15;
#pragma unroll
        for (int h = 0; h < 2; ++h) {
            aoff[t][h] = ar * 64 + (((h * 4 + qd) ^ (ar & 7)) * 8);
            boff[t][h] = br * 64 + (((h * 4 + qd) ^ (br & 7)) * 8);
        }
    }

    int nsteps = K >> 6;                       // 16
    for (int s = 0; s < nsteps; ++s) {
        int k0 = s << 6;
#pragma unroll
        for (int i = 0; i < 8; ++i)
            __builtin_amdgcn_global_load_lds(
                (__attribute__((address_space(1))) void*)(gsrc[i] + k0),
                (__attribute__((address_space(3))) void*)(ldst[i]), 16, 0, 0);
        WAIT_VMCNT0();
        __builtin_amdgcn_s_barrier();          // all waves' DMAs landed
        bf16x8 av[4][2], bv[4][2];
#pragma unroll
        for (int t = 0; t < 4; ++t)
#pragma unroll
            for (int h = 0; h < 2; ++h) {
                av[t][h] = *(const bf16x8*)&As[aoff[t][h]];
                bv[t][h] = *(const bf16x8*)&Bs[boff[t][h]];
            }
#pragma unroll
        for (int mt = 0; mt < 4; ++mt)
#pragma unroll
            for (int nt = 0; nt < 4; ++nt) {
                acc[mt][nt] = __builtin_amdgcn_mfma_f32_16x16x32_bf16(
                    av[mt][0], bv[nt][0], acc[mt][nt], 0, 0, 0);
                acc[mt][nt] = __builtin_amdgcn_mfma_f32_16x16x32_bf16(
                    av[mt][1], bv[nt][1], acc[mt][nt], 0, 0, 0);
            }
        __builtin_amdgcn_s_barrier();          // readers done before restage
    }

#pragma unroll
    for (int mt = 0; mt < 4; ++mt) {
        int row0 = m0 + wm * 64 + mt * 16 + qd * 4;
#pragma unroll
        for (int nt = 0; nt < 4; ++nt) {
            int col = n0 + wn * 64 + nt * 16 + l15;
            float v[4];
#pragma unroll
            for (int reg = 0; reg < 4; ++reg) {
                v[reg] = acc[mt][nt][reg] + bias[col];
                if (GELU) v[reg] = 0.5f * v[reg] * (1.f + erff(v[reg] * 0.70710678118654752f));
            }
            if (VSPLIT && col >= 2 * D_MODEL) {
                int d = col - 2 * D_MODEL;
                int bh = (row0 >> 11) * NH + (d >> 6);
                ushort4 pkv = {f2b(v[0]), f2b(v[1]), f2b(v[2]), f2b(v[3])};
                *(ushort4*)&vt[((size_t)(bh * DH + (d & 63))) * SEQ + (row0 & (SEQ - 1))] = pkv;
            } else {
#pragma unroll
                for (int reg = 0; reg < 4; ++reg)
                    Cb[(size_t)(row0 + reg) * ldc + col] = f2b(v[reg]);
            }
        }
    }
}

// ---------------------------------------------------------------- GEMM 128^2 dbuf
// R13: for FF2 (M=4096, N=1024, K=3072). R0's verified dbuf 128x128
// structure: grid = 32x8 = 256 = 1 block/CU; per-step compute (~64
// ds_read + 128 MFMA ~= 1000+ cyc) exceeds the ~900 cyc prefetch
// latency, so the one-step-ahead dbuf prefetch self-hides (the regime
// where dbuf works; R6's failure was short steps + occupancy loss).
// K=3072 -> 48 steps amortize fill/drain. bias + resid + f32 out.
__global__ __launch_bounds__(256) void gemm_wide_k(
        const u16* __restrict__ A, const u16* __restrict__ Bt,
        const float* __restrict__ bias, const float* __restrict__ resid,
        float* __restrict__ C, int M, int N, int K, int ldc) {
    __shared__ u16 As[2 * 128 * 64];           // 32 KiB
    __shared__ u16 Bs[2 * 128 * 64];           // 32 KiB
    int tid = threadIdx.x;
    int w = tid >> 6, lane = tid & 63;
    int qd = lane >> 4, l15 = lane & 15;

    // grid = (M/128)*(N/128) = 32*8 = 256. XCD-stripe: 4 m-tiles per XCD.
    int lin = blockIdx.x;
    int xcd = lin & 7, idx = lin >> 3;         // idx 0..31
    int m0 = (xcd * 4 + (idx & 3)) * 128;
    int n0 = (idx >> 2) * 128;

    // Staging: 32 chunks of 1 KiB; wave owns 8. 0-15 = A, 16-31 = B.
    const u16* gsrc[8];
    u16* ldst[8];
#pragma unroll
    for (int i = 0; i < 8; ++i) {
        int c = w * 8 + i;
        int cb = c & 15;
        int row = cb * 8 + (lane >> 3);
        int cg = (lane & 7) ^ (row & 7);       // XOR swizzle, global side
        gsrc[i] = (c < 16 ? A + (size_t)(m0 + row) * K
                          : Bt + (size_t)(n0 + row) * K) + cg * 8;
        ldst[i] = (c < 16 ? As : Bs) + cb * 512;
    }

    int wm = w & 1, wn = w >> 1;               // 2x2 waves, 64x64 each
    f32x4 acc[4][4];
#pragma unroll
    for (int mt = 0; mt < 4; ++mt)
#pragma unroll
        for (int nt = 0; nt < 4; ++nt)
            acc[mt][nt] = (f32x4){0.f, 0.f, 0.f, 0.f};

    int aoff[4][2], boff[4][2];
#pragma unroll
    for (int t = 0; t < 4; ++t) {
        int ar = wm * 64 + t * 16 + l15;
        int br = wn * 64 + t * 16 + l15;
#pragma unroll
        for (int h = 0; h < 2; ++h) {
            aoff[t][h] = ar * 64 + (((h * 4 + qd) ^ (ar & 7)) * 8);
            boff[t][h] = br * 64 + (((h * 4 + qd) ^ (br & 7)) * 8);
        }
    }

    // prologue: stage step 0 into buffer 0
#pragma unroll
    for (int i = 0; i < 8; ++i)
        __builtin_amdgcn_global_load_lds(
            (__attribute__((address_space(1))) void*)(gsrc[i]),
            (__attribute__((address_space(3))) void*)(ldst[i]), 16, 0, 0);

    int nsteps = K >> 6;                       // 48
    for (int s = 0; s < nsteps; ++s) {
        int cur = s & 1;
        WAIT_VMCNT0();                         // my cur-buffer DMA done
        __builtin_amdgcn_s_barrier();          // all waves staged cur &
                                               //   done reading other buf
        if (s + 1 < nsteps) {                  // wave-uniform branch
            int k0 = (s + 1) << 6;
            int boffs = (cur ^ 1) * 8192;
#pragma unroll
            for (int i = 0; i < 8; ++i)
                __builtin_amdgcn_global_load_lds(
                    (__attribute__((address_space(1))) void*)(gsrc[i] + k0),
                    (__attribute__((address_space(3))) void*)(ldst[i] + boffs),
                    16, 0, 0);
        }
        int off = cur * 8192;
        bf16x8 av[4][2], bv[4][2];
#pragma unroll
        for (int t = 0; t < 4; ++t)
#pragma unroll
            for (int h = 0; h < 2; ++h) {
                av[t][h] = *(const bf16x8*)&As[aoff[t][h] + off];
                bv[t][h] = *(const bf16x8*)&Bs[boff[t][h] + off];
            }
#pragma unroll
        for (int mt = 0; mt < 4; ++mt)
#pragma unroll
            for (int nt = 0; nt < 4; ++nt) {
                acc[mt][nt] = __builtin_amdgcn_mfma_f32_16x16x32_bf16(
                    av[mt][0], bv[nt][0], acc[mt][nt], 0, 0, 0);
                acc[mt][nt] = __builtin_amdgcn_mfma_f32_16x16x32_bf16(
                    av[mt][1], bv[nt][1], acc[mt][nt], 0, 0, 0);
            }
    }

#pragma unroll
    for (int mt = 0; mt < 4; ++mt) {
        int row0 = m0 + wm * 64 + mt * 16 + qd * 4;
#pragma unroll
        for (int nt = 0; nt < 4; ++nt) {
            int col = n0 + wn * 64 + nt * 16 + l15;
#pragma unroll
            for (int reg = 0; reg < 4; ++reg) {
                float v = acc[mt][nt][reg] + bias[col]
                        + resid[(size_t)(row0 + reg) * ldc + col];
                C[(size_t)(row0 + reg) * ldc + col] = v;
            }
        }
    }
}

// ---------------------------------------------------------------- GEMM 64x128
// For attn-out (M=4096, N=1024, K=1024). Grid = 512 blocks, 48 KiB LDS,
// dbuf; K=1024 is too short for 1-block/CU amortization so the 2-block
// cross-TLP config stays. bias + resid + f32 out. Per-wave 32x64.
__global__ __launch_bounds__(256, 3) void gemm_tall_k(
        const u16* __restrict__ A, const u16* __restrict__ Bt,
        const float* __restrict__ bias, const float* __restrict__ resid,
        float* __restrict__ C, int M, int N, int K, int ldc) {
    __shared__ u16 As[2 * 64 * 64];            // 16 KiB
    __shared__ u16 Bs[2 * 128 * 64];           // 32 KiB
    int tid = threadIdx.x;
    int w = tid >> 6, lane = tid & 63;
    int qd = lane >> 4, l15 = lane & 15;

    // grid = (M/64)*(N/128) = 64*8 = 512. XCD-stripe: 8 m-tiles per XCD.
    int lin = blockIdx.x;
    int xcd = lin & 7, idx = lin >> 3;         // idx 0..63
    int m0 = (xcd * 8 + (idx & 7)) * 64;
    int n0 = (idx >> 3) * 128;

    // Staging: 24 chunks of 1 KiB; wave owns 6. 0-7 = A, 8-23 = B.
    const u16* gsrc[6];
    u16* ldst[6];
    int nboff[6];                              // elem offset to buffer 1
#pragma unroll
    for (int i = 0; i < 6; ++i) {
        int c = w * 6 + i;                     // 0..23
        int isA = c < 8;
        int cb = isA ? c : c - 8;
        int row = cb * 8 + (lane >> 3);
        int cg = (lane & 7) ^ (row & 7);       // XOR swizzle, global side
        gsrc[i] = (isA ? A + (size_t)(m0 + row) * K
                       : Bt + (size_t)(n0 + row) * K) + cg * 8;
        ldst[i] = (isA ? As : Bs) + cb * 512;
        nboff[i] = isA ? 4096 : 8192;
    }

    int wm = w & 1, wn = w >> 1;               // 2x2 waves, 32x64 each
    f32x4 acc[2][4];
#pragma unroll
    for (int mt = 0; mt < 2; ++mt)
#pragma unroll
        for (int nt = 0; nt < 4; ++nt)
            acc[mt][nt] = (f32x4){0.f, 0.f, 0.f, 0.f};

    int aoff[2][2], boff[4][2];
#pragma unroll
    for (int t = 0; t < 2; ++t) {
        int ar = wm * 32 + t * 16 + l15;
#pragma unroll
        for (int h = 0; h < 2; ++h)
            aoff[t][h] = ar * 64 + (((h * 4 + qd) ^ (ar & 7)) * 8);
    }
#pragma unroll
    for (int t = 0; t < 4; ++t) {
        int br = wn * 64 + t * 16 + l15;
#pragma unroll
        for (int h = 0; h < 2; ++h)
            boff[t][h] = br * 64 + (((h * 4 + qd) ^ (br & 7)) * 8);
    }

    // prologue: stage step 0 into buffer 0
#pragma unroll
    for (int i = 0; i < 6; ++i)
        __builtin_amdgcn_global_load_lds(
            (__attribute__((address_space(1))) void*)(gsrc[i]),
            (__attribute__((address_space(3))) void*)(ldst[i]), 16, 0, 0);

    int nsteps = K >> 6;                       // 16

#define TSTEP64(S, RB)                                                      \
    {                                                                       \
        WAIT_VMCNT0();                                                      \
        __builtin_amdgcn_s_barrier();                                       \
        if ((S) + 1 < nsteps) {                                             \
            int k0 = ((S) + 1) << 6;                                        \
            _Pragma("unroll")                                               \
            for (int i = 0; i < 6; ++i)                                     \
                __builtin_amdgcn_global_load_lds(                           \
                    (__attribute__((address_space(1))) void*)(gsrc[i] + k0),\
                    (__attribute__((address_space(3))) void*)(ldst[i] +     \
                        (1 - (RB)) * nboff[i]),                             \
                    16, 0, 0);                                              \
        }                                                                   \
        bf16x8 av[2][2], bv[4][2];                                          \
        _Pragma("unroll")                                                   \
        for (int t = 0; t < 2; ++t)                                         \
            _Pragma("unroll")                                               \
            for (int h = 0; h < 2; ++h)                                     \
                av[t][h] = *(const bf16x8*)&As[aoff[t][h] + (RB) * 4096];   \
        _Pragma("unroll")                                                   \
        for (int t = 0; t < 4; ++t)                                         \
            _Pragma("unroll")                                               \
            for (int h = 0; h < 2; ++h)                                     \
                bv[t][h] = *(const bf16x8*)&Bs[boff[t][h] + (RB) * 8192];   \
        _Pragma("unroll")                                                   \
        for (int mt = 0; mt < 2; ++mt)                                      \
            _Pragma("unroll")                                               \
            for (int nt = 0; nt < 4; ++nt) {                                \
                acc[mt][nt] = __builtin_amdgcn_mfma_f32_16x16x32_bf16(      \
                    av[mt][0], bv[nt][0], acc[mt][nt], 0, 0, 0);            \
                acc[mt][nt] = __builtin_amdgcn_mfma_f32_16x16x32_bf16(      \
                    av[mt][1], bv[nt][1], acc[mt][nt], 0, 0, 0);            \
            }                                                               \
    }

    for (int s = 0; s < nsteps; s += 2) {
        TSTEP64(s, 0);
        TSTEP64(s + 1, 1);
    }

#pragma unroll
    for (int mt = 0; mt < 2; ++mt) {
        int row0 = m0 + wm * 32 + mt * 16 + qd * 4;
#pragma unroll
        for (int nt = 0; nt < 4; ++nt) {
            int col = n0 + wn * 64 + nt * 16 + l15;
#pragma unroll
            for (int reg = 0; reg < 4; ++reg) {
                float v = acc[mt][nt][reg] + bias[col]
                        + resid[(size_t)(row0 + reg) * ldc + col];
                C[(size_t)(row0 + reg) * ldc + col] = v;
            }
        }
    }
}

// ---------------------------------------------------------------- attention
// Flash-style MFMA; one wave per 16-query tile; <=5 chunks of 32 keys.
// qk buffer layout (bf16): [b, s, {q:0..1023, k:1024..2047}]
__global__ __launch_bounds__(256) void attn_k(
        const u16* __restrict__ qk, const u16* __restrict__ vt,
        u16* __restrict__ ctx) {
    int lane = threadIdx.x & 63, l15 = lane & 15, quad = lane >> 4;
    int t = blockIdx.x * 4 + (threadIdx.x >> 6);
    int qt = t & (SEQ / 16 - 1);
    int h  = (t >> 7) & (NH - 1);
    int b  = t >> 11;
    int q0 = qt * 16;
    int bh = b * NH + h;

    const u16* qrow = qk + (size_t)(b * SEQ + q0 + l15) * (2 * D_MODEL) + h * DH + quad * 8;
    bf16x8 qf0 = *(const bf16x8*)(qrow);
    bf16x8 qf1 = *(const bf16x8*)(qrow + 32);
    const u16* kbase = qk + (size_t)(b * SEQ) * (2 * D_MODEL) + D_MODEL + h * DH + quad * 8;
    const u16* vbase = vt + (size_t)(bh * DH) * SEQ;

    f32x4 o[4] = {{0.f, 0.f, 0.f, 0.f}, {0.f, 0.f, 0.f, 0.f},
                  {0.f, 0.f, 0.f, 0.f}, {0.f, 0.f, 0.f, 0.f}};
    float m = -1e30f, l = 0.f;
    int q = q0 + l15;
    int cs = q0 - (WIN - 1);
    cs = cs < 0 ? 0 : (cs & ~31);

    for (int c = cs; c <= q0 + 15; c += 32) {
        const u16* k0p = kbase + (size_t)(c + l15) * (2 * D_MODEL);
        const u16* k1p = k0p + (size_t)16 * (2 * D_MODEL);
        bf16x8 ka0 = *(const bf16x8*)(k0p);
        bf16x8 ka1 = *(const bf16x8*)(k0p + 32);
        bf16x8 kb0 = *(const bf16x8*)(k1p);
        bf16x8 kb1 = *(const bf16x8*)(k1p + 32);
        f32x4 s0 = {0.f, 0.f, 0.f, 0.f}, s1 = {0.f, 0.f, 0.f, 0.f};
        s0 = __builtin_amdgcn_mfma_f32_16x16x32_bf16(ka0, qf0, s0, 0, 0, 0);
        s0 = __builtin_amdgcn_mfma_f32_16x16x32_bf16(ka1, qf1, s0, 0, 0, 0);
        s1 = __builtin_amdgcn_mfma_f32_16x16x32_bf16(kb0, qf0, s1, 0, 0, 0);
        s1 = __builtin_amdgcn_mfma_f32_16x16x32_bf16(kb1, qf1, s1, 0, 0, 0);

        float p0[4], p1[4];
        float cm = -1e30f;
#pragma unroll
        for (int reg = 0; reg < 4; ++reg) {
            int k0i = c + quad * 4 + reg;
            p0[reg] = ((unsigned)(q - k0i) < WIN) ? s0[reg] * 0.125f : -1e30f;
            p1[reg] = ((unsigned)(q - k0i - 16) < WIN) ? s1[reg] * 0.125f : -1e30f;
            cm = fmaxf(cm, fmaxf(p0[reg], p1[reg]));
        }
        cm = fmaxf(cm, __shfl_xor(cm, 16, 64));
        cm = fmaxf(cm, __shfl_xor(cm, 32, 64));
        float mn = fmaxf(m, cm);
        float alpha = __expf(m - mn);
        m = mn;
        float ls = 0.f;
#pragma unroll
        for (int reg = 0; reg < 4; ++reg) {
            p0[reg] = __expf(p0[reg] - mn);
            p1[reg] = __expf(p1[reg] - mn);
            ls += p0[reg] + p1[reg];
        }
        ls += __shfl_xor(ls, 16, 64);
        ls += __shfl_xor(ls, 32, 64);
        l = l * alpha + ls;
#pragma unroll
        for (int mt = 0; mt < 4; ++mt) o[mt] *= alpha;

        u32 z0 = pk2(p0[0], p0[1]), z1 = pk2(p0[2], p0[3]);
        u32 w0 = pk2(p1[0], p1[1]), w1 = pk2(p1[2], p1[3]);
        int slo = ((quad & 1) * 2) * 16 + l15;
        int shi = slo + 16;
        u32 zl0 = (u32)__shfl((int)z0, slo, 64), zl1 = (u32)__shfl((int)z1, slo, 64);
        u32 zh0 = (u32)__shfl((int)z0, shi, 64), zh1 = (u32)__shfl((int)z1, shi, 64);
        u32 wl0 = (u32)__shfl((int)w0, slo, 64), wl1 = (u32)__shfl((int)w1, slo, 64);
        u32 wh0 = (u32)__shfl((int)w0, shi, 64), wh1 = (u32)__shfl((int)w1, shi, 64);
        alignas(16) u32 pr[4];
        pr[0] = quad < 2 ? zl0 : wl0;
        pr[1] = quad < 2 ? zl1 : wl1;
        pr[2] = quad < 2 ? zh0 : wh0;
        pr[3] = quad < 2 ? zh1 : wh1;
        bf16x8 pf = *(const bf16x8*)pr;

#pragma unroll
        for (int mt = 0; mt < 4; ++mt) {
            bf16x8 vf = *(const bf16x8*)(vbase + (size_t)(mt * 16 + l15) * SEQ + c + quad * 8);
            o[mt] = __builtin_amdgcn_mfma_f32_16x16x32_bf16(vf, pf, o[mt], 0, 0, 0);
        }
    }

    float rdiv = 1.f / l;
    u16* crow = ctx + (size_t)(b * SEQ + q0 + l15) * D_MODEL + h * DH;
#pragma unroll
    for (int mt = 0; mt < 4; ++mt) {
        ushort4 pkv = {f2b(o[mt][0] * rdiv), f2b(o[mt][1] * rdiv),
                       f2b(o[mt][2] * rdiv), f2b(o[mt][3] * rdiv)};
        *(ushort4*)(crow + mt * 16 + quad * 4) = pkv;
    }
}

// ---------------------------------------------------------------- launch
extern "C" void kernel_launch(void* const* d_in, const int* in_sizes, int n_in,
                              void* d_out, int out_size, void* d_ws, size_t ws_size,
                              hipStream_t stream) {
    (void)in_sizes; (void)n_in; (void)out_size; (void)ws_size;
    const float* x     = (const float*)d_in[0];
    const float* w_qkv = (const float*)d_in[1];
    const float* b_qkv = (const float*)d_in[2];
    const float* w_out = (const float*)d_in[3];
    const float* b_out = (const float*)d_in[4];
    const float* w_ff1 = (const float*)d_in[5];
    const float* b_ff1 = (const float*)d_in[6];
    const float* w_ff2 = (const float*)d_in[7];
    const float* b_ff2 = (const float*)d_in[8];
    const float* ln1g  = (const float*)d_in[9];
    const float* ln1b  = (const float*)d_in[10];
    const float* ln2g  = (const float*)d_in[11];
    const float* ln2b  = (const float*)d_in[12];
    float* out = (float*)d_out;

    const int M = BATCH * SEQ;                       // 4096
    char* base = (char*)d_ws;                        // 76 MiB peak
    u16*   hbf   = (u16*)(base);                     //  8 MiB: LN out
    u16*   qkbuf = (u16*)(base + (8ll  << 20));      // 16 MiB: Q,K [b,s,2048]
    u16*   ctxbf = (u16*)(base + (24ll << 20));      //  8 MiB: attn out
    u16*   vtbuf = (u16*)(base + (32ll << 20));      //  8 MiB: V^T [bh][d][s]
    u16*   ffbf  = (u16*)(base + (8ll  << 20));      // 24 MiB: FF inter (overlays qk+ctx, disjoint lifetime)
    float* x2    = (float*)(base + (40ll << 20));    // 16 MiB: f32 residual
    u16*   wqkvT = (u16*)(base + (56ll << 20));      //  6 MiB
    u16*   woutT = (u16*)(base + (62ll << 20));      //  2 MiB
    u16*   wff1T = (u16*)(base + (64ll << 20));      //  6 MiB
    u16*   wff2T = (u16*)(base + (70ll << 20));      //  6 MiB

    // fused: 4 weight transposes (64x64 tiles) + LN1 (all independent)
    prep_k<<<dim3(6656), 256, 0, stream>>>(
        x, ln1g, ln1b, hbf, w_qkv, wqkvT, w_out, woutT,
        w_ff1, wff1T, w_ff2, wff2T);
    // QKV: Q,K -> qkbuf (ldc 2048); V -> vtbuf transposed. 128x128, 768 blk.
    gemm3_k<0, 1><<<dim3((M / 128) * (3 * D_MODEL / 128)), 256, 0, stream>>>(
        hbf, wqkvT, b_qkv, qkbuf, vtbuf, M, 3 * D_MODEL, D_MODEL, 2 * D_MODEL);
    attn_k<<<dim3(BATCH * NH * (SEQ / 16) / 4), 256, 0, stream>>>(qkbuf, vtbuf, ctxbf);
    // x2 = x + ctx @ w_out + b_out   (64x128 tile, 512 blocks)
    gemm_tall_k<<<dim3(512), 256, 0, stream>>>(
        ctxbf, woutT, b_out, x, x2, M, D_MODEL, D_MODEL, D_MODEL);
    // hbf = bf16(LN2(x2))
    ln_k<<<M, 256, 0, stream>>>(x2, ln2g, ln2b, hbf);
    // ffbf = bf16(gelu(hbf @ w_ff1 + b_ff1))   (128x128, 768 blocks)
    gemm3_k<1, 0><<<dim3((M / 128) * (DFF / 128)), 256, 0, stream>>>(
        hbf, wff1T, b_ff1, ffbf, nullptr, M, DFF, D_MODEL, DFF);
    // out = x2 + ffbf @ w_ff2 + b_ff2   (128x128 dbuf, 256 blocks)
    gemm_wide_k<<<dim3(256), 256, 0, stream>>>(
        ffbf, wff2T, b_ff2, x2, out, M, D_MODEL, DFF, D_MODEL);
}

// Round 14
// 259.818 us; speedup vs baseline: 1.0186x; 1.0186x over previous
//
#include <hip/hip_runtime.h>

#define D_MODEL 1024
#define SEQ 2048
#define BATCH 2
#define NH 16
#define DH 64
#define WIN 128
#define DFF 3072

typedef __bf16 bf16x8 __attribute__((ext_vector_type(8)));
typedef float f32x4 __attribute__((ext_vector_type(4)));
typedef unsigned short u16;
typedef unsigned int u32;

__device__ __forceinline__ float b2f(u16 u) {
    unsigned int x = ((unsigned int)u) << 16;
    return __uint_as_float(x);
}
__device__ __forceinline__ u16 f2b(float f) {
    unsigned int x = __float_as_uint(f);
    x += 0x7fffu + ((x >> 16) & 1u);
    return (u16)(x >> 16);
}
__device__ __forceinline__ u32 pk2(float a, float b) {
    return (u32)f2b(a) | ((u32)f2b(b) << 16);
}

// s_waitcnt imm: vmcnt[3:0]|[15:14], exp[6:4], lgkm[11:8]. vmcnt(0), no
// exp/lgkm wait: 0x0F70.
#define WAIT_VMCNT0() __builtin_amdgcn_s_waitcnt(0x0F70)

// ---------------------------------------------------------------- prep
// Fused: 4 weight transposes (f32 -> bf16, [R][C] -> [C][R], 64x64 tiles,
// float4 reads, ushort4 stores) + LN1 (float4 loads).
// Ranges: [0,768) wqkv, [768,1024) wout, [1024,1792) wff1,
//         [1792,2560) wff2, [2560,6656) LN1 rows.
__global__ __launch_bounds__(256) void prep_k(
        const float* __restrict__ x, const float* __restrict__ g1,
        const float* __restrict__ bt1, u16* __restrict__ hbf,
        const float* __restrict__ wqkv, u16* __restrict__ wqkvT,
        const float* __restrict__ wout, u16* __restrict__ woutT,
        const float* __restrict__ wff1, u16* __restrict__ wff1T,
        const float* __restrict__ wff2, u16* __restrict__ wff2T) {
    __shared__ u16 tile[64][65];
    __shared__ float s1[4], s2[4];
    int bid = blockIdx.x;
    int tid = threadIdx.x;
    if (bid < 2560) {
        const float* in; u16* out; int R, C, loc, gx;
        if (bid < 768)       { in = wqkv; out = wqkvT; R = 1024; C = 3072; loc = bid;        gx = 48; }
        else if (bid < 1024) { in = wout; out = woutT; R = 1024; C = 1024; loc = bid - 768;  gx = 16; }
        else if (bid < 1792) { in = wff1; out = wff1T; R = 1024; C = 3072; loc = bid - 1024; gx = 48; }
        else                 { in = wff2; out = wff2T; R = 3072; C = 1024; loc = bid - 1792; gx = 16; }
        int bx = loc % gx, by = loc / gx;
        int r0 = by * 64, c0 = bx * 64;
        int fl = tid & 15, rw = tid >> 4;      // 16 float4-cols x 16 rows
#pragma unroll
        for (int j = 0; j < 4; ++j) {
            int r = j * 16 + rw;
            float4 v4 = *(const float4*)&in[(size_t)(r0 + r) * C + c0 + fl * 4];
            tile[r][fl * 4 + 0] = f2b(v4.x);
            tile[r][fl * 4 + 1] = f2b(v4.y);
            tile[r][fl * 4 + 2] = f2b(v4.z);
            tile[r][fl * 4 + 3] = f2b(v4.w);
        }
        __syncthreads();
        int rr = (tid & 15) * 4;
        int cb = tid >> 4;                     // 0..15
#pragma unroll
        for (int j = 0; j < 4; ++j) {
            int c = cb + j * 16;
            ushort4 p = {tile[rr][c], tile[rr + 1][c],
                         tile[rr + 2][c], tile[rr + 3][c]};
            *(ushort4*)&out[(size_t)(c0 + c) * R + r0 + rr] = p;
        }
    } else {
        int row = bid - 2560;
        float4 v = ((const float4*)(x + (size_t)row * D_MODEL))[tid];
        float sum = v.x + v.y + v.z + v.w;
        float sq  = v.x * v.x + v.y * v.y + v.z * v.z + v.w * v.w;
#pragma unroll
        for (int off = 32; off > 0; off >>= 1) {
            sum += __shfl_xor(sum, off, 64);
            sq  += __shfl_xor(sq, off, 64);
        }
        int w = tid >> 6;
        if ((tid & 63) == 0) { s1[w] = sum; s2[w] = sq; }
        __syncthreads();
        sum = s1[0] + s1[1] + s1[2] + s1[3];
        sq  = s2[0] + s2[1] + s2[2] + s2[3];
        float mu = sum * (1.f / D_MODEL);
        float var = sq * (1.f / D_MODEL) - mu * mu;
        float rstd = rsqrtf(var + 1e-5f);
        float4 gg = ((const float4*)g1)[tid];
        float4 bb = ((const float4*)bt1)[tid];
        ushort4 o = {f2b((v.x - mu) * rstd * gg.x + bb.x),
                     f2b((v.y - mu) * rstd * gg.y + bb.y),
                     f2b((v.z - mu) * rstd * gg.z + bb.z),
                     f2b((v.w - mu) * rstd * gg.w + bb.w)};
        *(ushort4*)&hbf[(size_t)row * D_MODEL + tid * 4] = o;
    }
}

// ---------------------------------------------------------------- layernorm
// float4 loads: 256 threads x 1 float4 = one 1024-wide row.
__global__ __launch_bounds__(256) void ln_k(
        const float* __restrict__ x, const float* __restrict__ g,
        const float* __restrict__ bta, u16* __restrict__ out) {
    int row = blockIdx.x;
    int tid = threadIdx.x;
    float4 v = ((const float4*)(x + (size_t)row * D_MODEL))[tid];
    float sum = v.x + v.y + v.z + v.w;
    float sq  = v.x * v.x + v.y * v.y + v.z * v.z + v.w * v.w;
#pragma unroll
    for (int off = 32; off > 0; off >>= 1) {
        sum += __shfl_xor(sum, off, 64);
        sq  += __shfl_xor(sq, off, 64);
    }
    __shared__ float s1[4], s2[4];
    int w = tid >> 6;
    if ((tid & 63) == 0) { s1[w] = sum; s2[w] = sq; }
    __syncthreads();
    sum = s1[0] + s1[1] + s1[2] + s1[3];
    sq  = s2[0] + s2[1] + s2[2] + s2[3];
    float mu = sum * (1.f / D_MODEL);
    float var = sq * (1.f / D_MODEL) - mu * mu;
    float rstd = rsqrtf(var + 1e-5f);
    float4 gg = ((const float4*)g)[tid];
    float4 bb = ((const float4*)bta)[tid];
    ushort4 o = {f2b((v.x - mu) * rstd * gg.x + bb.x),
                 f2b((v.y - mu) * rstd * gg.y + bb.y),
                 f2b((v.z - mu) * rstd * gg.z + bb.z),
                 f2b((v.w - mu) * rstd * gg.w + bb.w)};
    *(ushort4*)&out[(size_t)row * D_MODEL + tid * 4] = o;
}

// ---------------------------------------------------------------- GEMM 128^2
// For QKV/FF1 (N=3072). R12-proven (best wall 262.6): 128x128 tile,
// single-buffer skeleton {stage -> vmcnt(0) -> barrier -> ds_read+MFMA ->
// barrier}. 32 KiB LDS; grid = 32x24 = 768 = exactly 3 blocks/CU. 0.5
// ds_read/MFMA. XOR bank swizzle (conflicts=0). NO setprio (R10: 10x
// L2-thrash in lockstep).
template <int GELU, int VSPLIT>
__global__ __launch_bounds__(256, 3) void gemm3_k(
        const u16* __restrict__ A, const u16* __restrict__ Bt,
        const float* __restrict__ bias, u16* __restrict__ Cb,
        u16* __restrict__ vt, int M, int N, int K, int ldc) {
    __shared__ u16 As[128 * 64];               // 16 KiB
    __shared__ u16 Bs[128 * 64];               // 16 KiB
    int tid = threadIdx.x;
    int w = tid >> 6, lane = tid & 63;
    int qd = lane >> 4, l15 = lane & 15;

    // grid = (M/128)*(N/128) = 32*24 = 768. XCD-stripe: 4 m-tiles per XCD
    // (512-row, 1 MiB A stripe stays L2-local per XCD).
    int lin = blockIdx.x;
    int xcd = lin & 7, idx = lin >> 3;         // idx 0..95
    int m0 = (xcd * 4 + (idx & 3)) * 128;
    int n0 = (idx >> 2) * 128;

    // Staging: 32 chunks of 1 KiB (8 rows x 64 cols); wave owns 8.
    // chunks 0-15 = A (128 rows), 16-31 = B (128 rows).
    const u16* gsrc[8];
    u16* ldst[8];
#pragma unroll
    for (int i = 0; i < 8; ++i) {
        int c = w * 8 + i;                     // 0..31
        int cb = c & 15;
        int row = cb * 8 + (lane >> 3);
        int cg = (lane & 7) ^ (row & 7);       // XOR swizzle, global side
        gsrc[i] = (c < 16 ? A + (size_t)(m0 + row) * K
                          : Bt + (size_t)(n0 + row) * K) + cg * 8;
        ldst[i] = (c < 16 ? As : Bs) + cb * 512;
    }

    int wm = w & 1, wn = w >> 1;               // 2x2 waves, 64x64 each
    f32x4 acc[4][4];
#pragma unroll
    for (int mt = 0; mt < 4; ++mt)
#pragma unroll
        for (int nt = 0; nt < 4; ++nt)
            acc[mt][nt] = (f32x4){0.f, 0.f, 0.f, 0.f};

    int aoff[4][2], boff[4][2];
#pragma unroll
    for (int t = 0; t < 4; ++t) {
        int ar = wm * 64 + t * 16 + l15;
        int br = wn * 64 + t * 16 + l15;
#pragma unroll
        for (int h = 0; h < 2; ++h) {
            aoff[t][h] = ar * 64 + (((h * 4 + qd) ^ (ar & 7)) * 8);
            boff[t][h] = br * 64 + (((h * 4 + qd) ^ (br & 7)) * 8);
        }
    }

    int nsteps = K >> 6;                       // 16
    for (int s = 0; s < nsteps; ++s) {
        int k0 = s << 6;
#pragma unroll
        for (int i = 0; i < 8; ++i)
            __builtin_amdgcn_global_load_lds(
                (__attribute__((address_space(1))) void*)(gsrc[i] + k0),
                (__attribute__((address_space(3))) void*)(ldst[i]), 16, 0, 0);
        WAIT_VMCNT0();
        __builtin_amdgcn_s_barrier();          // all waves' DMAs landed
        bf16x8 av[4][2], bv[4][2];
#pragma unroll
        for (int t = 0; t < 4; ++t)
#pragma unroll
            for (int h = 0; h < 2; ++h) {
                av[t][h] = *(const bf16x8*)&As[aoff[t][h]];
                bv[t][h] = *(const bf16x8*)&Bs[boff[t][h]];
            }
#pragma unroll
        for (int mt = 0; mt < 4; ++mt)
#pragma unroll
            for (int nt = 0; nt < 4; ++nt) {
                acc[mt][nt] = __builtin_amdgcn_mfma_f32_16x16x32_bf16(
                    av[mt][0], bv[nt][0], acc[mt][nt], 0, 0, 0);
                acc[mt][nt] = __builtin_amdgcn_mfma_f32_16x16x32_bf16(
                    av[mt][1], bv[nt][1], acc[mt][nt], 0, 0, 0);
            }
        __builtin_amdgcn_s_barrier();          // readers done before restage
    }

#pragma unroll
    for (int mt = 0; mt < 4; ++mt) {
        int row0 = m0 + wm * 64 + mt * 16 + qd * 4;
#pragma unroll
        for (int nt = 0; nt < 4; ++nt) {
            int col = n0 + wn * 64 + nt * 16 + l15;
            float v[4];
#pragma unroll
            for (int reg = 0; reg < 4; ++reg) {
                v[reg] = acc[mt][nt][reg] + bias[col];
                if (GELU) v[reg] = 0.5f * v[reg] * (1.f + erff(v[reg] * 0.70710678118654752f));
            }
            if (VSPLIT && col >= 2 * D_MODEL) {
                int d = col - 2 * D_MODEL;
                int bh = (row0 >> 11) * NH + (d >> 6);
                ushort4 pkv = {f2b(v[0]), f2b(v[1]), f2b(v[2]), f2b(v[3])};
                *(ushort4*)&vt[((size_t)(bh * DH + (d & 63))) * SEQ + (row0 & (SEQ - 1))] = pkv;
            } else {
#pragma unroll
                for (int reg = 0; reg < 4; ++reg)
                    Cb[(size_t)(row0 + reg) * ldc + col] = f2b(v[reg]);
            }
        }
    }
}

// ---------------------------------------------------------------- GEMM 64x128
// For the N=1024 GEMMs (attn-out, FF2). Grid = 512 blocks, 48 KiB LDS
// dbuf -> 3 blocks/CU (grid-limited to 2). bias + resid + f32 out.
// Per-wave 32x64, acc[2][4]. No setprio (R10 lesson). R13's 128^2
// 1-block/CU dbuf variant for FF2 was neutral-to-worse (no cross-block
// cover for fill/drain at 1 blk/CU) -> reverted here.
__global__ __launch_bounds__(256, 3) void gemm_tall_k(
        const u16* __restrict__ A, const u16* __restrict__ Bt,
        const float* __restrict__ bias, const float* __restrict__ resid,
        float* __restrict__ C, int M, int N, int K, int ldc) {
    __shared__ u16 As[2 * 64 * 64];            // 16 KiB
    __shared__ u16 Bs[2 * 128 * 64];           // 32 KiB
    int tid = threadIdx.x;
    int w = tid >> 6, lane = tid & 63;
    int qd = lane >> 4, l15 = lane & 15;

    // grid = (M/64)*(N/128) = 64*8 = 512. XCD-stripe: 8 m-tiles per XCD.
    int lin = blockIdx.x;
    int xcd = lin & 7, idx = lin >> 3;         // idx 0..63
    int m0 = (xcd * 8 + (idx & 7)) * 64;
    int n0 = (idx >> 3) * 128;

    // Staging: 24 chunks of 1 KiB (8 rows x 64 cols); wave owns 6.
    // chunks 0-7 = A (64 rows), 8-23 = B (128 rows).
    const u16* gsrc[6];
    u16* ldst[6];
    int nboff[6];                              // elem offset to buffer 1
#pragma unroll
    for (int i = 0; i < 6; ++i) {
        int c = w * 6 + i;                     // 0..23
        int isA = c < 8;
        int cb = isA ? c : c - 8;
        int row = cb * 8 + (lane >> 3);
        int cg = (lane & 7) ^ (row & 7);       // XOR swizzle, global side
        gsrc[i] = (isA ? A + (size_t)(m0 + row) * K
                       : Bt + (size_t)(n0 + row) * K) + cg * 8;
        ldst[i] = (isA ? As : Bs) + cb * 512;
        nboff[i] = isA ? 4096 : 8192;
    }

    int wm = w & 1, wn = w >> 1;               // 2x2 waves, 32x64 each
    f32x4 acc[2][4];
#pragma unroll
    for (int mt = 0; mt < 2; ++mt)
#pragma unroll
        for (int nt = 0; nt < 4; ++nt)
            acc[mt][nt] = (f32x4){0.f, 0.f, 0.f, 0.f};

    int aoff[2][2], boff[4][2];
#pragma unroll
    for (int t = 0; t < 2; ++t) {
        int ar = wm * 32 + t * 16 + l15;
#pragma unroll
        for (int h = 0; h < 2; ++h)
            aoff[t][h] = ar * 64 + (((h * 4 + qd) ^ (ar & 7)) * 8);
    }
#pragma unroll
    for (int t = 0; t < 4; ++t) {
        int br = wn * 64 + t * 16 + l15;
#pragma unroll
        for (int h = 0; h < 2; ++h)
            boff[t][h] = br * 64 + (((h * 4 + qd) ^ (br & 7)) * 8);
    }

    // prologue: stage step 0 into buffer 0
#pragma unroll
    for (int i = 0; i < 6; ++i)
        __builtin_amdgcn_global_load_lds(
            (__attribute__((address_space(1))) void*)(gsrc[i]),
            (__attribute__((address_space(3))) void*)(ldst[i]), 16, 0, 0);

    int nsteps = K >> 6;                       // 16 or 48, always even

#define TSTEP64(S, RB)                                                      \
    {                                                                       \
        WAIT_VMCNT0();                                                      \
        __builtin_amdgcn_s_barrier();                                       \
        if ((S) + 1 < nsteps) {                                             \
            int k0 = ((S) + 1) << 6;                                        \
            _Pragma("unroll")                                               \
            for (int i = 0; i < 6; ++i)                                     \
                __builtin_amdgcn_global_load_lds(                           \
                    (__attribute__((address_space(1))) void*)(gsrc[i] + k0),\
                    (__attribute__((address_space(3))) void*)(ldst[i] +     \
                        (1 - (RB)) * nboff[i]),                             \
                    16, 0, 0);                                              \
        }                                                                   \
        bf16x8 av[2][2], bv[4][2];                                          \
        _Pragma("unroll")                                                   \
        for (int t = 0; t < 2; ++t)                                         \
            _Pragma("unroll")                                               \
            for (int h = 0; h < 2; ++h)                                     \
                av[t][h] = *(const bf16x8*)&As[aoff[t][h] + (RB) * 4096];   \
        _Pragma("unroll")                                                   \
        for (int t = 0; t < 4; ++t)                                         \
            _Pragma("unroll")                                               \
            for (int h = 0; h < 2; ++h)                                     \
                bv[t][h] = *(const bf16x8*)&Bs[boff[t][h] + (RB) * 8192];   \
        _Pragma("unroll")                                                   \
        for (int mt = 0; mt < 2; ++mt)                                      \
            _Pragma("unroll")                                               \
            for (int nt = 0; nt < 4; ++nt) {                                \
                acc[mt][nt] = __builtin_amdgcn_mfma_f32_16x16x32_bf16(      \
                    av[mt][0], bv[nt][0], acc[mt][nt], 0, 0, 0);            \
                acc[mt][nt] = __builtin_amdgcn_mfma_f32_16x16x32_bf16(      \
                    av[mt][1], bv[nt][1], acc[mt][nt], 0, 0, 0);            \
            }                                                               \
    }

    for (int s = 0; s < nsteps; s += 2) {
        TSTEP64(s, 0);
        TSTEP64(s + 1, 1);
    }

#pragma unroll
    for (int mt = 0; mt < 2; ++mt) {
        int row0 = m0 + wm * 32 + mt * 16 + qd * 4;
#pragma unroll
        for (int nt = 0; nt < 4; ++nt) {
            int col = n0 + wn * 64 + nt * 16 + l15;
#pragma unroll
            for (int reg = 0; reg < 4; ++reg) {
                float v = acc[mt][nt][reg] + bias[col]
                        + resid[(size_t)(row0 + reg) * ldc + col];
                C[(size_t)(row0 + reg) * ldc + col] = v;
            }
        }
    }
}

// ---------------------------------------------------------------- attention
// Flash-style MFMA; one wave per 16-query tile; <=5 chunks of 32 keys.
// qk buffer layout (bf16): [b, s, {q:0..1023, k:1024..2047}]
__global__ __launch_bounds__(256) void attn_k(
        const u16* __restrict__ qk, const u16* __restrict__ vt,
        u16* __restrict__ ctx) {
    int lane = threadIdx.x & 63, l15 = lane & 15, quad = lane >> 4;
    int t = blockIdx.x * 4 + (threadIdx.x >> 6);
    int qt = t & (SEQ / 16 - 1);
    int h  = (t >> 7) & (NH - 1);
    int b  = t >> 11;
    int q0 = qt * 16;
    int bh = b * NH + h;

    const u16* qrow = qk + (size_t)(b * SEQ + q0 + l15) * (2 * D_MODEL) + h * DH + quad * 8;
    bf16x8 qf0 = *(const bf16x8*)(qrow);
    bf16x8 qf1 = *(const bf16x8*)(qrow + 32);
    const u16* kbase = qk + (size_t)(b * SEQ) * (2 * D_MODEL) + D_MODEL + h * DH + quad * 8;
    const u16* vbase = vt + (size_t)(bh * DH) * SEQ;

    f32x4 o[4] = {{0.f, 0.f, 0.f, 0.f}, {0.f, 0.f, 0.f, 0.f},
                  {0.f, 0.f, 0.f, 0.f}, {0.f, 0.f, 0.f, 0.f}};
    float m = -1e30f, l = 0.f;
    int q = q0 + l15;
    int cs = q0 - (WIN - 1);
    cs = cs < 0 ? 0 : (cs & ~31);

    for (int c = cs; c <= q0 + 15; c += 32) {
        const u16* k0p = kbase + (size_t)(c + l15) * (2 * D_MODEL);
        const u16* k1p = k0p + (size_t)16 * (2 * D_MODEL);
        bf16x8 ka0 = *(const bf16x8*)(k0p);
        bf16x8 ka1 = *(const bf16x8*)(k0p + 32);
        bf16x8 kb0 = *(const bf16x8*)(k1p);
        bf16x8 kb1 = *(const bf16x8*)(k1p + 32);
        f32x4 s0 = {0.f, 0.f, 0.f, 0.f}, s1 = {0.f, 0.f, 0.f, 0.f};
        s0 = __builtin_amdgcn_mfma_f32_16x16x32_bf16(ka0, qf0, s0, 0, 0, 0);
        s0 = __builtin_amdgcn_mfma_f32_16x16x32_bf16(ka1, qf1, s0, 0, 0, 0);
        s1 = __builtin_amdgcn_mfma_f32_16x16x32_bf16(kb0, qf0, s1, 0, 0, 0);
        s1 = __builtin_amdgcn_mfma_f32_16x16x32_bf16(kb1, qf1, s1, 0, 0, 0);

        float p0[4], p1[4];
        float cm = -1e30f;
#pragma unroll
        for (int reg = 0; reg < 4; ++reg) {
            int k0i = c + quad * 4 + reg;
            p0[reg] = ((unsigned)(q - k0i) < WIN) ? s0[reg] * 0.125f : -1e30f;
            p1[reg] = ((unsigned)(q - k0i - 16) < WIN) ? s1[reg] * 0.125f : -1e30f;
            cm = fmaxf(cm, fmaxf(p0[reg], p1[reg]));
        }
        cm = fmaxf(cm, __shfl_xor(cm, 16, 64));
        cm = fmaxf(cm, __shfl_xor(cm, 32, 64));
        float mn = fmaxf(m, cm);
        float alpha = __expf(m - mn);
        m = mn;
        float ls = 0.f;
#pragma unroll
        for (int reg = 0; reg < 4; ++reg) {
            p0[reg] = __expf(p0[reg] - mn);
            p1[reg] = __expf(p1[reg] - mn);
            ls += p0[reg] + p1[reg];
        }
        ls += __shfl_xor(ls, 16, 64);
        ls += __shfl_xor(ls, 32, 64);
        l = l * alpha + ls;
#pragma unroll
        for (int mt = 0; mt < 4; ++mt) o[mt] *= alpha;

        u32 z0 = pk2(p0[0], p0[1]), z1 = pk2(p0[2], p0[3]);
        u32 w0 = pk2(p1[0], p1[1]), w1 = pk2(p1[2], p1[3]);
        int slo = ((quad & 1) * 2) * 16 + l15;
        int shi = slo + 16;
        u32 zl0 = (u32)__shfl((int)z0, slo, 64), zl1 = (u32)__shfl((int)z1, slo, 64);
        u32 zh0 = (u32)__shfl((int)z0, shi, 64), zh1 = (u32)__shfl((int)z1, shi, 64);
        u32 wl0 = (u32)__shfl((int)w0, slo, 64), wl1 = (u32)__shfl((int)w1, slo, 64);
        u32 wh0 = (u32)__shfl((int)w0, shi, 64), wh1 = (u32)__shfl((int)w1, shi, 64);
        alignas(16) u32 pr[4];
        pr[0] = quad < 2 ? zl0 : wl0;
        pr[1] = quad < 2 ? zl1 : wl1;
        pr[2] = quad < 2 ? zh0 : wh0;
        pr[3] = quad < 2 ? zh1 : wh1;
        bf16x8 pf = *(const bf16x8*)pr;

#pragma unroll
        for (int mt = 0; mt < 4; ++mt) {
            bf16x8 vf = *(const bf16x8*)(vbase + (size_t)(mt * 16 + l15) * SEQ + c + quad * 8);
            o[mt] = __builtin_amdgcn_mfma_f32_16x16x32_bf16(vf, pf, o[mt], 0, 0, 0);
        }
    }

    float rdiv = 1.f / l;
    u16* crow = ctx + (size_t)(b * SEQ + q0 + l15) * D_MODEL + h * DH;
#pragma unroll
    for (int mt = 0; mt < 4; ++mt) {
        ushort4 pkv = {f2b(o[mt][0] * rdiv), f2b(o[mt][1] * rdiv),
                       f2b(o[mt][2] * rdiv), f2b(o[mt][3] * rdiv)};
        *(ushort4*)(crow + mt * 16 + quad * 4) = pkv;
    }
}

// ---------------------------------------------------------------- launch
extern "C" void kernel_launch(void* const* d_in, const int* in_sizes, int n_in,
                              void* d_out, int out_size, void* d_ws, size_t ws_size,
                              hipStream_t stream) {
    (void)in_sizes; (void)n_in; (void)out_size; (void)ws_size;
    const float* x     = (const float*)d_in[0];
    const float* w_qkv = (const float*)d_in[1];
    const float* b_qkv = (const float*)d_in[2];
    const float* w_out = (const float*)d_in[3];
    const float* b_out = (const float*)d_in[4];
    const float* w_ff1 = (const float*)d_in[5];
    const float* b_ff1 = (const float*)d_in[6];
    const float* w_ff2 = (const float*)d_in[7];
    const float* b_ff2 = (const float*)d_in[8];
    const float* ln1g  = (const float*)d_in[9];
    const float* ln1b  = (const float*)d_in[10];
    const float* ln2g  = (const float*)d_in[11];
    const float* ln2b  = (const float*)d_in[12];
    float* out = (float*)d_out;

    const int M = BATCH * SEQ;                       // 4096
    char* base = (char*)d_ws;                        // 76 MiB peak
    u16*   hbf   = (u16*)(base);                     //  8 MiB: LN out
    u16*   qkbuf = (u16*)(base + (8ll  << 20));      // 16 MiB: Q,K [b,s,2048]
    u16*   ctxbf = (u16*)(base + (24ll << 20));      //  8 MiB: attn out
    u16*   vtbuf = (u16*)(base + (32ll << 20));      //  8 MiB: V^T [bh][d][s]
    u16*   ffbf  = (u16*)(base + (8ll  << 20));      // 24 MiB: FF inter (overlays qk+ctx, disjoint lifetime)
    float* x2    = (float*)(base + (40ll << 20));    // 16 MiB: f32 residual
    u16*   wqkvT = (u16*)(base + (56ll << 20));      //  6 MiB
    u16*   woutT = (u16*)(base + (62ll << 20));      //  2 MiB
    u16*   wff1T = (u16*)(base + (64ll << 20));      //  6 MiB
    u16*   wff2T = (u16*)(base + (70ll << 20));      //  6 MiB

    // fused: 4 weight transposes (64x64 tiles) + LN1 (all independent)
    prep_k<<<dim3(6656), 256, 0, stream>>>(
        x, ln1g, ln1b, hbf, w_qkv, wqkvT, w_out, woutT,
        w_ff1, wff1T, w_ff2, wff2T);
    // QKV: Q,K -> qkbuf (ldc 2048); V -> vtbuf transposed. 128x128, 768 blk.
    gemm3_k<0, 1><<<dim3((M / 128) * (3 * D_MODEL / 128)), 256, 0, stream>>>(
        hbf, wqkvT, b_qkv, qkbuf, vtbuf, M, 3 * D_MODEL, D_MODEL, 2 * D_MODEL);
    attn_k<<<dim3(BATCH * NH * (SEQ / 16) / 4), 256, 0, stream>>>(qkbuf, vtbuf, ctxbf);
    // x2 = x + ctx @ w_out + b_out   (64x128 tile, 512 blocks)
    gemm_tall_k<<<dim3(512), 256, 0, stream>>>(
        ctxbf, woutT, b_out, x, x2, M, D_MODEL, D_MODEL, D_MODEL);
    // hbf = bf16(LN2(x2))
    ln_k<<<M, 256, 0, stream>>>(x2, ln2g, ln2b, hbf);
    // ffbf = bf16(gelu(hbf @ w_ff1 + b_ff1))   (128x128, 768 blocks)
    gemm3_k<1, 0><<<dim3((M / 128) * (DFF / 128)), 256, 0, stream>>>(
        hbf, wff1T, b_ff1, ffbf, nullptr, M, DFF, D_MODEL, DFF);
    // out = x2 + ffbf @ w_ff2 + b_ff2   (64x128 tile, 512 blocks)
    gemm_tall_k<<<dim3(512), 256, 0, stream>>>(
        ffbf, wff2T, b_ff2, x2, out, M, D_MODEL, DFF, D_MODEL);
}